// Round 9
// baseline (424.892 us; speedup 1.0000x reference)
//
#include <hip/hip_runtime.h>
#include <hip/hip_bf16.h>
#include <math.h>

typedef short bf16x8 __attribute__((ext_vector_type(8)));
typedef float f32x4 __attribute__((ext_vector_type(4)));
typedef unsigned short u16;
typedef unsigned short u16x8v __attribute__((ext_vector_type(8)));

#define DEVI __device__ __forceinline__
#define SCHED_FENCE() __builtin_amdgcn_sched_barrier(0)

DEVI u16 f2b(float x) {
  __hip_bfloat16 h = __float2bfloat16(x);
  return *reinterpret_cast<u16*>(&h);
}

DEVI void load_lds16(const void* g, void* l) {
  __builtin_amdgcn_global_load_lds(
      (__attribute__((address_space(1))) void*)(void*)g,
      (__attribute__((address_space(3))) void*)l, 16, 0, 0);
}

// ---------------------------------------------------------------------------
// 128x128 tile, BK=32, 256 thr / 4 waves (2x2, 64x64/wave).
// Deep-pipelined K-loop: 3 LDS slots (16KB each: A[128][32] + B[128][32]),
// prefetch distance 2, counted vmcnt(4) (= 1 stage group of 4 loads in
// flight) -- never vmcnt(0) in steady state.  Raw s_barrier (NOT
// __syncthreads, which drains vmcnt to 0 and defeats the pipeline).
// XOR swizzle at 16B granule: granule (row,q) stored at quad q^((row>>1)&3);
// global source pre-swizzled per-lane, reads apply same XOR (rule #21).
// Slot-reuse safety: stage(t+2) writes slot (t+2)%3, last READ in iteration
// t-1; those reads are consumed by MFMAs before the end-of-(t-1) barrier,
// so every wave finished reading before any wave stages over it.
// Does NOT zero acc (caller inits; callable twice for concat-K).
// ---------------------------------------------------------------------------
DEVI void gemm_core(const u16* __restrict__ A, int lda,
                    const u16* __restrict__ Bw, int ldb,
                    int K, int m0, int n0,
                    u16* lds, f32x4 (&acc)[4][4])
{
  const int tid = threadIdx.x;
  const int w = tid >> 6, l = tid & 63;
  const int wr = w >> 1, wc = w & 1;
  const int lr = l & 15, kg = l >> 4;
  const int c0 = w * 2;
  const int srow = l >> 2, kq = l & 3;

  // read offsets within a slot (A at +0, B at +4096)
  int aoff[4], boff[4];
#pragma unroll
  for (int m = 0; m < 4; ++m) {
    int ra = wr * 64 + m * 16 + lr;
    aoff[m] = ra * 32 + ((kg ^ ((ra >> 1) & 3)) << 3);
    int rb = wc * 64 + m * 16 + lr;
    boff[m] = 4096 + rb * 32 + ((kg ^ ((rb >> 1) & 3)) << 3);
  }

  // staging geometry (per-lane global srcs, wave-uniform LDS dests)
  const int row0 = (c0 + 0) * 16 + srow;
  const int row1 = (c0 + 1) * 16 + srow;
  const int kc0 = (kq ^ ((row0 >> 1) & 3)) << 3;
  const int kc1 = (kq ^ ((row1 >> 1) & 3)) << 3;
  const u16* aS0 = A + (long)(m0 + row0) * lda + kc0;
  const u16* aS1 = A + (long)(m0 + row1) * lda + kc1;
  const u16* bS0 = Bw + (long)(n0 + row0) * ldb + kc0;
  const u16* bS1 = Bw + (long)(n0 + row1) * ldb + kc1;
  const int dA0 = (c0 + 0) * 512, dA1 = (c0 + 1) * 512;
  const int dB0 = 4096 + dA0,     dB1 = 4096 + dA1;

  const int nt = K >> 5;

  auto stage = [&](int t, u16* slot) {
    const int gk = t * 32;
    load_lds16(aS0 + gk, slot + dA0);
    load_lds16(aS1 + gk, slot + dA1);
    load_lds16(bS0 + gk, slot + dB0);
    load_lds16(bS1 + gk, slot + dB1);
  };

  u16* p0 = lds;            // slot holding tile t
  u16* p1 = lds + 8192;     // tile t+1
  u16* p2 = lds + 16384;    // tile t+2 (being staged)

  // prologue: tiles 0 and 1 (ordered so vmcnt(4) == "tile 0 landed")
  stage(0, p0);
  SCHED_FENCE();
  stage(1, p1);
  SCHED_FENCE();
  asm volatile("s_waitcnt vmcnt(4)" ::: "memory");
  SCHED_FENCE();
  __builtin_amdgcn_s_barrier();
  SCHED_FENCE();

  for (int t = 0; t < nt; ++t) {
    bf16x8 af[4], bfr[4];
#pragma unroll
    for (int m = 0; m < 4; ++m)
      af[m] = *reinterpret_cast<const bf16x8*>(&p0[aoff[m]]);
#pragma unroll
    for (int n = 0; n < 4; ++n)
      bfr[n] = *reinterpret_cast<const bf16x8*>(&p0[boff[n]]);

    const bool pre = (t + 2 < nt);
    if (pre) stage(t + 2, p2);

#pragma unroll
    for (int m = 0; m < 4; ++m)
#pragma unroll
      for (int n = 0; n < 4; ++n)
        acc[m][n] = __builtin_amdgcn_mfma_f32_16x16x32_bf16(af[m], bfr[n], acc[m][n], 0, 0, 0);

    SCHED_FENCE();
    if (pre) asm volatile("s_waitcnt vmcnt(4)" ::: "memory");
    else     asm volatile("s_waitcnt vmcnt(0)" ::: "memory");
    SCHED_FENCE();
    __builtin_amdgcn_s_barrier();
    SCHED_FENCE();

    u16* tmp = p0; p0 = p1; p1 = p2; p2 = tmp;  // rotate slots
  }
}

#define ZERO_ACC(acc) \
  _Pragma("unroll") for (int m = 0; m < 4; ++m) \
  _Pragma("unroll") for (int n = 0; n < 4; ++n) acc[m][n] = (f32x4)0.f;

// XCD-chunked bijective grid decode (nwg % 8 == 0, 32 M-rows, M-fastest):
// each XCD owns a contiguous id2 range = ~nwg/(8*32) complete weight columns,
// so that column's weight panel stays resident in the XCD's private L2.
// (Best measured variant: R5.  Col-fastest (R8) regressed -- do not revisit.)
#define GRID_DECODE() \
  const int per = (int)gridDim.x >> 3; \
  const int id2 = ((int)blockIdx.x & 7) * per + ((int)blockIdx.x >> 3); \
  const int bx = id2 >> 5; \
  const int m0 = (id2 & 31) * 128;

#define EPI_VARS() \
  const int tid = threadIdx.x; \
  const int w = tid >> 6, l = tid & 63; \
  const int wr = w >> 1, wc = w & 1; \
  const int lr = l & 15, kg = l >> 4;

// Launch A: bx<16 -> G1 new_hidden ; bx==16 -> G2 mid
__global__ __launch_bounds__(256, 3)
void gemmA(const u16* __restrict__ cmb,
           const u16* __restrict__ wch2b, const float* __restrict__ bch2,
           const u16* __restrict__ wcm2b, const float* __restrict__ bcm2,
           float* __restrict__ out_nh, u16* __restrict__ nhb,
           u16* __restrict__ midb)
{
  __shared__ u16 lds[3 * 8192];  // 48 KB -> 3 blocks/CU
  GRID_DECODE();
  EPI_VARS();
  f32x4 acc[4][4];
  ZERO_ACC(acc);

  if (bx < 16) {
    const int n0 = bx * 128;
    gemm_core(cmb, 7168, wch2b, 7168, 7168, m0, n0, lds, acc);
#pragma unroll
    for (int m = 0; m < 4; ++m) {
      const int r0 = m0 + wr * 64 + m * 16 + kg * 4;
#pragma unroll
      for (int n = 0; n < 4; ++n) {
        const int gc = n0 + wc * 64 + n * 16 + lr;
        const float b1 = bch2[gc];
#pragma unroll
        for (int j2 = 0; j2 < 4; ++j2) {
          const long idx = (long)(r0 + j2) * 2048 + gc;
          float v = acc[m][n][j2] + b1;
          out_nh[idx] = v; nhb[idx] = f2b(v);
        }
      }
    }
  } else {
    gemm_core(cmb, 7168, wcm2b, 7168, 7168, m0, 0, lds, acc);
#pragma unroll
    for (int m = 0; m < 4; ++m) {
      const int r0 = m0 + wr * 64 + m * 16 + kg * 4;
#pragma unroll
      for (int n = 0; n < 4; ++n) {
        const int gc = wc * 64 + n * 16 + lr;
        const float b1 = (gc < 100) ? bcm2[gc] : 0.0f;
#pragma unroll
        for (int j2 = 0; j2 < 4; ++j2) {
          float v = acc[m][n][j2] + b1;
          midb[(long)(r0 + j2) * 128 + gc] = f2b(v > 0.f ? v : 0.f);
        }
      }
    }
  }
}

// Launch B: bx<16 -> fused {h_proj ; lc = [nh|x]@[Wch|Wci]^T + biases}
//           bx>=16 -> G3 out
__global__ __launch_bounds__(256, 3)
void gemmB(const u16* __restrict__ nhb, const u16* __restrict__ wchb,
           const float* __restrict__ bch,
           const u16* __restrict__ cmb, const u16* __restrict__ wcib,
           const float* __restrict__ bci, const float* __restrict__ bias,
           float* __restrict__ out_ph, u16* __restrict__ lcb,
           const u16* __restrict__ midb, const u16* __restrict__ wmob,
           const float* __restrict__ bmo, float* __restrict__ out_out)
{
  __shared__ u16 lds[3 * 8192];
  GRID_DECODE();
  EPI_VARS();
  f32x4 acc[4][4];
  ZERO_ACC(acc);

  if (bx < 16) {
    const int n0 = bx * 128;
    // part 1: h_proj = nh @ Wch^T  (K=2048)
    gemm_core(nhb, 2048, wchb, 2048, 2048, m0, n0, lds, acc);
    // write out_ph = h_proj + bch BEFORE continuing accumulation
#pragma unroll
    for (int m = 0; m < 4; ++m) {
      const int r0 = m0 + wr * 64 + m * 16 + kg * 4;
#pragma unroll
      for (int n = 0; n < 4; ++n) {
        const int gc = n0 + wc * 64 + n * 16 + lr;
        const float b1 = bch[gc];
#pragma unroll
        for (int j2 = 0; j2 < 4; ++j2)
          out_ph[(long)(r0 + j2) * 2048 + gc] = acc[m][n][j2] + b1;
      }
    }
    // part 2: += x @ Wci^T  (K=1024; x = first 1024 cols of cmb)
    gemm_core(cmb, 7168, wcib, 1024, 1024, m0, n0, lds, acc);
#pragma unroll
    for (int m = 0; m < 4; ++m) {
      const int r0 = m0 + wr * 64 + m * 16 + kg * 4;
#pragma unroll
      for (int n = 0; n < 4; ++n) {
        const int gc = n0 + wc * 64 + n * 16 + lr;
        const float b1 = bch[gc] + bci[gc] + bias[gc];
#pragma unroll
        for (int j2 = 0; j2 < 4; ++j2)
          lcb[(long)(r0 + j2) * 2048 + gc] = f2b(acc[m][n][j2] + b1);
      }
    }
  } else {
    const int n0 = (bx - 16) * 128;
    gemm_core(midb, 128, wmob, 128, 128, m0, n0, lds, acc);
#pragma unroll
    for (int m = 0; m < 4; ++m) {
      const int r0 = m0 + wr * 64 + m * 16 + kg * 4;
#pragma unroll
      for (int n = 0; n < 4; ++n) {
        const int gc = n0 + wc * 64 + n * 16 + lr;
        const float b1 = bmo[gc];
#pragma unroll
        for (int j2 = 0; j2 < 4; ++j2)
          out_out[(long)(r0 + j2) * 256 + gc] = acc[m][n][j2] + b1;
      }
    }
  }
}

// Launch D: new_cell = tanh(lc @ W_fc^T + b_fc)
__global__ __launch_bounds__(256, 3)
void gemmD(const u16* __restrict__ lcb, const u16* __restrict__ wfcb,
           const float* __restrict__ bfc, float* __restrict__ out_cell)
{
  __shared__ u16 lds[3 * 8192];
  GRID_DECODE();
  const int n0 = bx * 128;
  EPI_VARS();
  f32x4 acc[4][4];
  ZERO_ACC(acc);

  gemm_core(lcb, 2048, wfcb, 2048, 2048, m0, n0, lds, acc);
#pragma unroll
  for (int m = 0; m < 4; ++m) {
    const int r0 = m0 + wr * 64 + m * 16 + kg * 4;
#pragma unroll
    for (int n = 0; n < 4; ++n) {
      const int gc = n0 + wc * 64 + n * 16 + lr;
      const float b1 = bfc[gc];
#pragma unroll
      for (int j2 = 0; j2 < 4; ++j2)
        out_cell[(long)(r0 + j2) * 2048 + gc] = tanhf(acc[m][n][j2] + b1);
    }
  }
}

// combined = [input | hidden | prev_hidden | cell] fp32 -> bf16, 8 elems/thread
__global__ void cvt_in(const float* __restrict__ x_in, const float* __restrict__ x_hid,
                       const float* __restrict__ x_ph, const float* __restrict__ x_cel,
                       u16* __restrict__ cmb)
{
  const long total = (long)4096 * 896;
  for (long i = blockIdx.x * (long)blockDim.x + threadIdx.x; i < total;
       i += (long)gridDim.x * blockDim.x) {
    const int c8 = (int)(i % 896);
    const long row = i / 896;
    const float* src; long sidx;
    if (c8 < 128)      { src = x_in;  sidx = row * 1024 + (long)c8 * 8; }
    else if (c8 < 384) { src = x_hid; sidx = row * 2048 + (long)(c8 - 128) * 8; }
    else if (c8 < 640) { src = x_ph;  sidx = row * 2048 + (long)(c8 - 384) * 8; }
    else               { src = x_cel; sidx = row * 2048 + (long)(c8 - 640) * 8; }
    float4 v0 = *reinterpret_cast<const float4*>(src + sidx);
    float4 v1 = *reinterpret_cast<const float4*>(src + sidx + 4);
    u16x8v o;
    o[0] = f2b(v0.x); o[1] = f2b(v0.y); o[2] = f2b(v0.z); o[3] = f2b(v0.w);
    o[4] = f2b(v1.x); o[5] = f2b(v1.y); o[6] = f2b(v1.z); o[7] = f2b(v1.w);
    *reinterpret_cast<u16x8v*>(&cmb[row * 7168 + (long)c8 * 8]) = o;
  }
}

// 5 contiguous fp32->bf16 weight segments in one kernel
__global__ void cvt_w5(const float* __restrict__ s0, const float* __restrict__ s1,
                       const float* __restrict__ s2, const float* __restrict__ s3,
                       const float* __restrict__ s4,
                       u16* __restrict__ d0, u16* __restrict__ d1, u16* __restrict__ d2,
                       u16* __restrict__ d3, u16* __restrict__ d4,
                       long e0, long e1, long e2, long e3, long e4)
{
  for (long i = blockIdx.x * (long)blockDim.x + threadIdx.x; i < e4;
       i += (long)gridDim.x * blockDim.x) {
    const float* s; u16* d; long j;
    if (i < e0)      { s = s0; d = d0; j = i; }
    else if (i < e1) { s = s1; d = d1; j = i - e0; }
    else if (i < e2) { s = s2; d = d2; j = i - e1; }
    else if (i < e3) { s = s3; d = d3; j = i - e2; }
    else             { s = s4; d = d4; j = i - e3; }
    float4 v = reinterpret_cast<const float4*>(s)[j];
    ushort4 o; o.x = f2b(v.x); o.y = f2b(v.y); o.z = f2b(v.z); o.w = f2b(v.w);
    reinterpret_cast<ushort4*>(d)[j] = o;
  }
}

// W_mo [256][100] fp32 -> [256][128] bf16 (cols 100..127 pre-zeroed by memset)
__global__ void cvt_wmo(const float* __restrict__ src, u16* __restrict__ dst)
{
  int i = blockIdx.x * blockDim.x + threadIdx.x;
  if (i < 256 * 100) {
    int r = i / 100, c = i - r * 100;
    dst[r * 128 + c] = f2b(src[i]);
  }
}

extern "C" void kernel_launch(void* const* d_in, const int* in_sizes, int n_in,
                              void* d_out, int out_size, void* d_ws, size_t ws_size,
                              hipStream_t stream) {
  const int B = 4096, I = 1024, H = 2048, O = 256;
  const int K1 = I + 3 * H;  // 7168

  const float* x_in  = (const float*)d_in[0];
  const float* x_hid = (const float*)d_in[1];
  const float* x_ph  = (const float*)d_in[2];
  const float* x_cel = (const float*)d_in[3];
  const float* Wch2  = (const float*)d_in[4];
  const float* bch2  = (const float*)d_in[5];
  const float* Wcm2  = (const float*)d_in[6];
  const float* bcm2  = (const float*)d_in[7];
  const float* Wmo   = (const float*)d_in[8];
  const float* bmo   = (const float*)d_in[9];
  const float* Wci   = (const float*)d_in[10];
  const float* bci   = (const float*)d_in[11];
  const float* Wch   = (const float*)d_in[12];
  const float* bch   = (const float*)d_in[13];
  const float* Wfc   = (const float*)d_in[14];
  const float* bfc   = (const float*)d_in[15];
  const float* bias  = (const float*)d_in[16];

  float* out_out  = (float*)d_out;                 // [B,O]
  float* out_nh   = out_out + (long)B * O;         // [B,H]
  float* out_cell = out_nh + (long)B * H;          // [B,H]
  float* out_ph   = out_cell + (long)B * H;        // [B,H]

  char* p = (char*)d_ws;
  u16* cmb   = (u16*)p; p += (long)B * K1 * 2;
  u16* wch2b = (u16*)p; p += (long)H * K1 * 2;
  u16* wcm2b = (u16*)p; p += (long)128 * K1 * 2;   // 100 rows + 28 zero-pad rows
  u16* wmob  = (u16*)p; p += (long)O * 128 * 2;    // K padded to 128
  u16* wcib  = (u16*)p; p += (long)H * I * 2;
  u16* wchb  = (u16*)p; p += (long)H * H * 2;
  u16* wfcb  = (u16*)p; p += (long)H * H * 2;
  u16* nhb   = (u16*)p; p += (long)B * H * 2;
  u16* midb  = (u16*)p; p += (long)B * 128 * 2;
  u16* lcb   = (u16*)p; p += (long)B * H * 2;

  const dim3 cb(256);

  // zero wcm2b pad rows + all of wmob in one shot (adjacent in ws)
  hipMemsetAsync(wcm2b + (long)100 * K1, 0, (size_t)(28 * K1 + 256 * 128) * 2, stream);

  cvt_in<<<2048, cb, 0, stream>>>(x_in, x_hid, x_ph, x_cel, cmb);
  {
    long e0 = (long)H * K1 / 4;
    long e1 = e0 + (long)100 * K1 / 4;
    long e2 = e1 + (long)H * I / 4;
    long e3 = e2 + (long)H * H / 4;
    long e4 = e3 + (long)H * H / 4;
    cvt_w5<<<2048, cb, 0, stream>>>(Wch2, Wcm2, Wci, Wch, Wfc,
                                    wch2b, wcm2b, wcib, wchb, wfcb,
                                    e0, e1, e2, e3, e4);
  }
  cvt_wmo<<<100, cb, 0, stream>>>(Wmo, wmob);

  // A: {new_hidden | mid}  -- 17 cols x 32 M-tiles = 544 blocks
  gemmA<<<dim3(17 * 32), cb, 0, stream>>>(cmb, wch2b, bch2, wcm2b, bcm2,
                                          out_nh, nhb, midb);
  // B: {h_proj + fused lc (concat-K) | out} -- 18 x 32 = 576 blocks
  gemmB<<<dim3(18 * 32), cb, 0, stream>>>(nhb, wchb, bch, cmb, wcib, bci, bias,
                                          out_ph, lcb, midb, wmob, bmo, out_out);
  // D: new_cell -- 16 x 32 = 512 blocks
  gemmD<<<dim3(16 * 32), cb, 0, stream>>>(lcb, wfcb, bfc, out_cell);

  (void)in_sizes; (void)n_in; (void)out_size; (void)ws_size;
}

// Round 10
// 373.042 us; speedup vs baseline: 1.1390x; 1.1390x over previous
//
#include <hip/hip_runtime.h>
#include <hip/hip_bf16.h>
#include <math.h>

typedef short bf16x8 __attribute__((ext_vector_type(8)));
typedef float f32x4 __attribute__((ext_vector_type(4)));
typedef unsigned short u16;
typedef unsigned short u16x8v __attribute__((ext_vector_type(8)));

#define DEVI __device__ __forceinline__

DEVI u16 f2b(float x) {
  __hip_bfloat16 h = __float2bfloat16(x);
  return *reinterpret_cast<u16*>(&h);
}

DEVI void load_lds16(const void* g, void* l) {
  __builtin_amdgcn_global_load_lds(
      (__attribute__((address_space(1))) void*)(void*)g,
      (__attribute__((address_space(3))) void*)l, 16, 0, 0);
}

// 128x128 tile, BK=64 (2 K-halves per barrier pair), 256 thr / 4 waves
// (2x2, 64x64 per wave).  LDS: As[2 kh][128 rows][32 elems], Bs same
// (16KB each).  XOR-swizzle at 16B granule within each kh: granule (row,q)
// lives at linear quad q ^ ((row>>1)&3); global_load_lds writes linearly so
// the GLOBAL source column is pre-swizzled per-lane (rule #21), reads apply
// the same XOR.  32 MFMA per barrier pair.  Does NOT zero acc (caller inits;
// may be called twice for concatenated-K accumulation).
// [R9 post-mortem: this 2-barrier structure at 128^2 is the best measured
// config; deep pipelines (R3, R9), smaller tiles (R6), and col-fastest
// banding (R8) all regressed.  Do not revisit without new evidence.]
DEVI void gemm_core(const u16* __restrict__ A, int lda,
                    const u16* __restrict__ Bw, int ldb,
                    int K, int m0, int n0,
                    u16* As, u16* Bs, f32x4 (&acc)[4][4])
{
  const int tid = threadIdx.x;
  const int w = tid >> 6, l = tid & 63;
  const int wr = w >> 1, wc = w & 1;
  const int lr = l & 15, kg = l >> 4;
  const int c0 = w * 2;
  const int srow = l >> 2, kq = l & 3;

  // read offsets within one kh-plane (plane stride 4096 elems)
  int aoff[4], boff[4];
#pragma unroll
  for (int m = 0; m < 4; ++m) {
    int ra = wr * 64 + m * 16 + lr;
    aoff[m] = ra * 32 + ((kg ^ ((ra >> 1) & 3)) << 3);
    int rb = wc * 64 + m * 16 + lr;
    boff[m] = rb * 32 + ((kg ^ ((rb >> 1) & 3)) << 3);
  }

  // staging geometry: chunk c = c0+i covers rows c*16..c*16+15 of a kh-plane
  const int row0 = (c0 + 0) * 16 + srow;
  const int row1 = (c0 + 1) * 16 + srow;
  const int kc0 = (kq ^ ((row0 >> 1) & 3)) << 3;
  const int kc1 = (kq ^ ((row1 >> 1) & 3)) << 3;
  const u16* aS0 = A + (long)(m0 + row0) * lda + kc0;
  const u16* aS1 = A + (long)(m0 + row1) * lda + kc1;
  const u16* bS0 = Bw + (long)(n0 + row0) * ldb + kc0;
  const u16* bS1 = Bw + (long)(n0 + row1) * ldb + kc1;
  u16* aD0 = &As[(c0 + 0) * 512];
  u16* aD1 = &As[(c0 + 1) * 512];
  u16* bD0 = &Bs[(c0 + 0) * 512];
  u16* bD1 = &Bs[(c0 + 1) * 512];

  for (int k0 = 0; k0 < K; k0 += 64) {
    __syncthreads();  // previous reads done before overwriting LDS
#pragma unroll
    for (int kh = 0; kh < 2; ++kh) {
      const int gk = k0 + kh * 32;
      const int lk = kh * 4096;
      load_lds16(aS0 + gk, aD0 + lk);
      load_lds16(aS1 + gk, aD1 + lk);
      load_lds16(bS0 + gk, bD0 + lk);
      load_lds16(bS1 + gk, bD1 + lk);
    }
    __syncthreads();  // vmcnt(0) drained by compiler before barrier

#pragma unroll
    for (int ks = 0; ks < 2; ++ks) {
      bf16x8 af[4], bfr[4];
#pragma unroll
      for (int m = 0; m < 4; ++m)
        af[m] = *reinterpret_cast<const bf16x8*>(&As[ks * 4096 + aoff[m]]);
#pragma unroll
      for (int n = 0; n < 4; ++n)
        bfr[n] = *reinterpret_cast<const bf16x8*>(&Bs[ks * 4096 + boff[n]]);
#pragma unroll
      for (int m = 0; m < 4; ++m)
#pragma unroll
        for (int n = 0; n < 4; ++n)
          acc[m][n] = __builtin_amdgcn_mfma_f32_16x16x32_bf16(af[m], bfr[n], acc[m][n], 0, 0, 0);
    }
  }
}

#define ZERO_ACC(acc) \
  _Pragma("unroll") for (int m = 0; m < 4; ++m) \
  _Pragma("unroll") for (int n = 0; n < 4; ++n) acc[m][n] = (f32x4)0.f;

// XCD-chunked bijective grid decode (nwg % 8 == 0, 32 M-rows, M-fastest):
// each XCD owns a contiguous id2 range = ~nwg/(8*32) complete weight columns,
// so that column's weight panel stays resident in the XCD's private L2.
// (Best measured variant: R5/R7.  Col-fastest (R8) regressed.)
#define GRID_DECODE() \
  const int per = (int)gridDim.x >> 3; \
  const int id2 = ((int)blockIdx.x & 7) * per + ((int)blockIdx.x >> 3); \
  const int bx = id2 >> 5; \
  const int m0 = (id2 & 31) * 128;

#define EPI_VARS() \
  const int tid = threadIdx.x; \
  const int w = tid >> 6, l = tid & 63; \
  const int wr = w >> 1, wc = w & 1; \
  const int lr = l & 15, kg = l >> 4;

// Launch A: bx<16 -> G1 new_hidden ; bx==16 -> G2 mid
__global__ __launch_bounds__(256, 4)
void gemmA(const u16* __restrict__ cmb,
           const u16* __restrict__ wch2b, const float* __restrict__ bch2,
           const u16* __restrict__ wcm2b, const float* __restrict__ bcm2,
           float* __restrict__ out_nh, u16* __restrict__ nhb,
           u16* __restrict__ midb)
{
  __shared__ u16 As[2 * 128 * 32], Bs[2 * 128 * 32];
  GRID_DECODE();
  EPI_VARS();
  f32x4 acc[4][4];
  ZERO_ACC(acc);

  if (bx < 16) {
    const int n0 = bx * 128;
    gemm_core(cmb, 7168, wch2b, 7168, 7168, m0, n0, As, Bs, acc);
#pragma unroll
    for (int m = 0; m < 4; ++m) {
      const int r0 = m0 + wr * 64 + m * 16 + kg * 4;
#pragma unroll
      for (int n = 0; n < 4; ++n) {
        const int gc = n0 + wc * 64 + n * 16 + lr;
        const float b1 = bch2[gc];
#pragma unroll
        for (int j2 = 0; j2 < 4; ++j2) {
          const long idx = (long)(r0 + j2) * 2048 + gc;
          float v = acc[m][n][j2] + b1;
          out_nh[idx] = v; nhb[idx] = f2b(v);
        }
      }
    }
  } else {
    gemm_core(cmb, 7168, wcm2b, 7168, 7168, m0, 0, As, Bs, acc);
#pragma unroll
    for (int m = 0; m < 4; ++m) {
      const int r0 = m0 + wr * 64 + m * 16 + kg * 4;
#pragma unroll
      for (int n = 0; n < 4; ++n) {
        const int gc = wc * 64 + n * 16 + lr;
        const float b1 = (gc < 100) ? bcm2[gc] : 0.0f;
#pragma unroll
        for (int j2 = 0; j2 < 4; ++j2) {
          float v = acc[m][n][j2] + b1;
          midb[(long)(r0 + j2) * 128 + gc] = f2b(v > 0.f ? v : 0.f);
        }
      }
    }
  }
}

// Launch B: bx<16 -> fused {h_proj ; lc = [nh|x]@[Wch|Wci]^T + biases}
//           bx>=16 -> G3 out
__global__ __launch_bounds__(256, 4)
void gemmB(const u16* __restrict__ nhb, const u16* __restrict__ wchb,
           const float* __restrict__ bch,
           const u16* __restrict__ cmb, const u16* __restrict__ wcib,
           const float* __restrict__ bci, const float* __restrict__ bias,
           float* __restrict__ out_ph, u16* __restrict__ lcb,
           const u16* __restrict__ midb, const u16* __restrict__ wmob,
           const float* __restrict__ bmo, float* __restrict__ out_out)
{
  __shared__ u16 As[2 * 128 * 32], Bs[2 * 128 * 32];
  GRID_DECODE();
  EPI_VARS();
  f32x4 acc[4][4];
  ZERO_ACC(acc);

  if (bx < 16) {
    const int n0 = bx * 128;
    // part 1: h_proj = nh @ Wch^T  (K=2048)
    gemm_core(nhb, 2048, wchb, 2048, 2048, m0, n0, As, Bs, acc);
    // write out_ph = h_proj + bch BEFORE continuing accumulation
#pragma unroll
    for (int m = 0; m < 4; ++m) {
      const int r0 = m0 + wr * 64 + m * 16 + kg * 4;
#pragma unroll
      for (int n = 0; n < 4; ++n) {
        const int gc = n0 + wc * 64 + n * 16 + lr;
        const float b1 = bch[gc];
#pragma unroll
        for (int j2 = 0; j2 < 4; ++j2)
          out_ph[(long)(r0 + j2) * 2048 + gc] = acc[m][n][j2] + b1;
      }
    }
    // part 2: += x @ Wci^T  (K=1024; x = first 1024 cols of cmb)
    gemm_core(cmb, 7168, wcib, 1024, 1024, m0, n0, As, Bs, acc);
#pragma unroll
    for (int m = 0; m < 4; ++m) {
      const int r0 = m0 + wr * 64 + m * 16 + kg * 4;
#pragma unroll
      for (int n = 0; n < 4; ++n) {
        const int gc = n0 + wc * 64 + n * 16 + lr;
        const float b1 = bch[gc] + bci[gc] + bias[gc];
#pragma unroll
        for (int j2 = 0; j2 < 4; ++j2)
          lcb[(long)(r0 + j2) * 2048 + gc] = f2b(acc[m][n][j2] + b1);
      }
    }
  } else {
    const int n0 = (bx - 16) * 128;
    gemm_core(midb, 128, wmob, 128, 128, m0, n0, As, Bs, acc);
#pragma unroll
    for (int m = 0; m < 4; ++m) {
      const int r0 = m0 + wr * 64 + m * 16 + kg * 4;
#pragma unroll
      for (int n = 0; n < 4; ++n) {
        const int gc = n0 + wc * 64 + n * 16 + lr;
        const float b1 = bmo[gc];
#pragma unroll
        for (int j2 = 0; j2 < 4; ++j2)
          out_out[(long)(r0 + j2) * 256 + gc] = acc[m][n][j2] + b1;
      }
    }
  }
}

// Launch D: new_cell = tanh(lc @ W_fc^T + b_fc)
__global__ __launch_bounds__(256, 4)
void gemmD(const u16* __restrict__ lcb, const u16* __restrict__ wfcb,
           const float* __restrict__ bfc, float* __restrict__ out_cell)
{
  __shared__ u16 As[2 * 128 * 32], Bs[2 * 128 * 32];
  GRID_DECODE();
  const int n0 = bx * 128;
  EPI_VARS();
  f32x4 acc[4][4];
  ZERO_ACC(acc);

  gemm_core(lcb, 2048, wfcb, 2048, 2048, m0, n0, As, Bs, acc);
#pragma unroll
  for (int m = 0; m < 4; ++m) {
    const int r0 = m0 + wr * 64 + m * 16 + kg * 4;
#pragma unroll
    for (int n = 0; n < 4; ++n) {
      const int gc = n0 + wc * 64 + n * 16 + lr;
      const float b1 = bfc[gc];
#pragma unroll
      for (int j2 = 0; j2 < 4; ++j2)
        out_cell[(long)(r0 + j2) * 2048 + gc] = tanhf(acc[m][n][j2] + b1);
    }
  }
}

// combined = [input | hidden | prev_hidden | cell] fp32 -> bf16, 8 elems/thread
__global__ void cvt_in(const float* __restrict__ x_in, const float* __restrict__ x_hid,
                       const float* __restrict__ x_ph, const float* __restrict__ x_cel,
                       u16* __restrict__ cmb)
{
  const long total = (long)4096 * 896;
  for (long i = blockIdx.x * (long)blockDim.x + threadIdx.x; i < total;
       i += (long)gridDim.x * blockDim.x) {
    const int c8 = (int)(i % 896);
    const long row = i / 896;
    const float* src; long sidx;
    if (c8 < 128)      { src = x_in;  sidx = row * 1024 + (long)c8 * 8; }
    else if (c8 < 384) { src = x_hid; sidx = row * 2048 + (long)(c8 - 128) * 8; }
    else if (c8 < 640) { src = x_ph;  sidx = row * 2048 + (long)(c8 - 384) * 8; }
    else               { src = x_cel; sidx = row * 2048 + (long)(c8 - 640) * 8; }
    float4 v0 = *reinterpret_cast<const float4*>(src + sidx);
    float4 v1 = *reinterpret_cast<const float4*>(src + sidx + 4);
    u16x8v o;
    o[0] = f2b(v0.x); o[1] = f2b(v0.y); o[2] = f2b(v0.z); o[3] = f2b(v0.w);
    o[4] = f2b(v1.x); o[5] = f2b(v1.y); o[6] = f2b(v1.z); o[7] = f2b(v1.w);
    *reinterpret_cast<u16x8v*>(&cmb[row * 7168 + (long)c8 * 8]) = o;
  }
}

// 5 contiguous fp32->bf16 weight segments in one kernel
__global__ void cvt_w5(const float* __restrict__ s0, const float* __restrict__ s1,
                       const float* __restrict__ s2, const float* __restrict__ s3,
                       const float* __restrict__ s4,
                       u16* __restrict__ d0, u16* __restrict__ d1, u16* __restrict__ d2,
                       u16* __restrict__ d3, u16* __restrict__ d4,
                       long e0, long e1, long e2, long e3, long e4)
{
  for (long i = blockIdx.x * (long)blockDim.x + threadIdx.x; i < e4;
       i += (long)gridDim.x * blockDim.x) {
    const float* s; u16* d; long j;
    if (i < e0)      { s = s0; d = d0; j = i; }
    else if (i < e1) { s = s1; d = d1; j = i - e0; }
    else if (i < e2) { s = s2; d = d2; j = i - e1; }
    else if (i < e3) { s = s3; d = d3; j = i - e2; }
    else             { s = s4; d = d4; j = i - e3; }
    float4 v = reinterpret_cast<const float4*>(s)[j];
    ushort4 o; o.x = f2b(v.x); o.y = f2b(v.y); o.z = f2b(v.z); o.w = f2b(v.w);
    reinterpret_cast<ushort4*>(d)[j] = o;
  }
}

// W_mo [256][100] fp32 -> [256][128] bf16 (cols 100..127 pre-zeroed by memset)
__global__ void cvt_wmo(const float* __restrict__ src, u16* __restrict__ dst)
{
  int i = blockIdx.x * blockDim.x + threadIdx.x;
  if (i < 256 * 100) {
    int r = i / 100, c = i - r * 100;
    dst[r * 128 + c] = f2b(src[i]);
  }
}

extern "C" void kernel_launch(void* const* d_in, const int* in_sizes, int n_in,
                              void* d_out, int out_size, void* d_ws, size_t ws_size,
                              hipStream_t stream) {
  const int B = 4096, I = 1024, H = 2048, O = 256;
  const int K1 = I + 3 * H;  // 7168

  const float* x_in  = (const float*)d_in[0];
  const float* x_hid = (const float*)d_in[1];
  const float* x_ph  = (const float*)d_in[2];
  const float* x_cel = (const float*)d_in[3];
  const float* Wch2  = (const float*)d_in[4];
  const float* bch2  = (const float*)d_in[5];
  const float* Wcm2  = (const float*)d_in[6];
  const float* bcm2  = (const float*)d_in[7];
  const float* Wmo   = (const float*)d_in[8];
  const float* bmo   = (const float*)d_in[9];
  const float* Wci   = (const float*)d_in[10];
  const float* bci   = (const float*)d_in[11];
  const float* Wch   = (const float*)d_in[12];
  const float* bch   = (const float*)d_in[13];
  const float* Wfc   = (const float*)d_in[14];
  const float* bfc   = (const float*)d_in[15];
  const float* bias  = (const float*)d_in[16];

  float* out_out  = (float*)d_out;                 // [B,O]
  float* out_nh   = out_out + (long)B * O;         // [B,H]
  float* out_cell = out_nh + (long)B * H;          // [B,H]
  float* out_ph   = out_cell + (long)B * H;        // [B,H]

  char* p = (char*)d_ws;
  u16* cmb   = (u16*)p; p += (long)B * K1 * 2;
  u16* wch2b = (u16*)p; p += (long)H * K1 * 2;
  u16* wcm2b = (u16*)p; p += (long)128 * K1 * 2;   // 100 rows + 28 zero-pad rows
  u16* wmob  = (u16*)p; p += (long)O * 128 * 2;    // K padded to 128
  u16* wcib  = (u16*)p; p += (long)H * I * 2;
  u16* wchb  = (u16*)p; p += (long)H * H * 2;
  u16* wfcb  = (u16*)p; p += (long)H * H * 2;
  u16* nhb   = (u16*)p; p += (long)B * H * 2;
  u16* midb  = (u16*)p; p += (long)B * 128 * 2;
  u16* lcb   = (u16*)p; p += (long)B * H * 2;

  const dim3 cb(256);

  // zero wcm2b pad rows + all of wmob in one shot (adjacent in ws)
  hipMemsetAsync(wcm2b + (long)100 * K1, 0, (size_t)(28 * K1 + 256 * 128) * 2, stream);

  cvt_in<<<2048, cb, 0, stream>>>(x_in, x_hid, x_ph, x_cel, cmb);
  {
    long e0 = (long)H * K1 / 4;
    long e1 = e0 + (long)100 * K1 / 4;
    long e2 = e1 + (long)H * I / 4;
    long e3 = e2 + (long)H * H / 4;
    long e4 = e3 + (long)H * H / 4;
    cvt_w5<<<2048, cb, 0, stream>>>(Wch2, Wcm2, Wci, Wch, Wfc,
                                    wch2b, wcm2b, wcib, wchb, wfcb,
                                    e0, e1, e2, e3, e4);
  }
  cvt_wmo<<<100, cb, 0, stream>>>(Wmo, wmob);

  // A: {new_hidden | mid}  -- 17 cols x 32 M-tiles = 544 blocks
  gemmA<<<dim3(17 * 32), cb, 0, stream>>>(cmb, wch2b, bch2, wcm2b, bcm2,
                                          out_nh, nhb, midb);
  // B: {h_proj + fused lc (concat-K) | out} -- 18 x 32 = 576 blocks
  gemmB<<<dim3(18 * 32), cb, 0, stream>>>(nhb, wchb, bch, cmb, wcib, bci, bias,
                                          out_ph, lcb, midb, wmob, bmo, out_out);
  // D: new_cell -- 16 x 32 = 512 blocks
  gemmD<<<dim3(16 * 32), cb, 0, stream>>>(lcb, wfcb, bfc, out_cell);

  (void)in_sizes; (void)n_in; (void)out_size; (void)ws_size;
}